// Round 12
// baseline (174.074 us; speedup 1.0000x reference)
//
#include <hip/hip_runtime.h>

typedef float f32x4 __attribute__((ext_vector_type(4)));
typedef __bf16 bf16x8 __attribute__((ext_vector_type(8)));
typedef __bf16 bf16x4 __attribute__((ext_vector_type(4)));

#define B_ 4
#define T_ 2048
#define D_ 1024
#define H_ 16
#define HD_ 64

__device__ __forceinline__ void gload_lds16(const void* g, void* l) {
  __builtin_amdgcn_global_load_lds(
      (const __attribute__((address_space(1))) void*)g,
      (__attribute__((address_space(3))) void*)l, 16, 0, 0);
}

// ---------------------------------------------------------------- convert x
__global__ __launch_bounds__(256) void k_cvt_f32_bf16(
    const float* __restrict__ in, __bf16* __restrict__ out, int n4) {
  int i = blockIdx.x * blockDim.x + threadIdx.x;
  int stride = gridDim.x * blockDim.x;
  for (; i < n4; i += stride) {
    float4 v = reinterpret_cast<const float4*>(in)[i];
    bf16x4 o = { (__bf16)v.x, (__bf16)v.y, (__bf16)v.z, (__bf16)v.w };
    reinterpret_cast<bf16x4*>(out)[i] = o;
  }
}

// ------------------------------------------- transpose (+convert) to bf16
template <typename Tin>
__global__ __launch_bounds__(256) void k_transpose_bf16(
    const Tin* __restrict__ in, __bf16* __restrict__ out,
    int R, int C, long inb, long outb) {
  __shared__ alignas(16) __bf16 lds[64 * 68];
  const int t = threadIdx.x;
  in  += (long)blockIdx.z * inb;
  out += (long)blockIdx.z * outb;
  const int r0 = blockIdx.y * 64, c0 = blockIdx.x * 64;
#pragma unroll
  for (int i = 0; i < 16; ++i) {
    int e = i * 256 + t, row = e >> 6, col = e & 63;
    lds[row * 68 + col] = (__bf16)(float)in[(long)(r0 + row) * C + c0 + col];
  }
  __syncthreads();
#pragma unroll
  for (int i = 0; i < 16; ++i) {
    int e = i * 256 + t, orow = e >> 6, ocol = e & 63;
    out[(long)(c0 + orow) * R + r0 + ocol] = lds[ocol * 68 + orow];
  }
}

// ---------------------------------------------------------------- GEMM (bt)
// 128x128 tile, BK=32, 256 thr, double-buffered LDS, 2-phase overlap,
// XOR-swizzled LDS (pre-swizzled global source + XOR'd read slot).
template <int EPI>
__global__ __launch_bounds__(256) void k_gemm_bt(
    const __bf16* __restrict__ A, const __bf16* __restrict__ Bt,
    const float* __restrict__ bias, void* __restrict__ Cout,
    __bf16* __restrict__ vout, int M, int N, int K) {
  __shared__ alignas(16) __bf16 As[2][128 * 32];
  __shared__ alignas(16) __bf16 Bs[2][128 * 32];
  const int t = threadIdx.x;
  const int w = t >> 6, l = t & 63;
  const int g = l >> 4, r16 = l & 15;
  const int wr = w >> 1, wc = w & 1;
  const int m0 = blockIdx.y * 128, n0 = blockIdx.x * 128;

  f32x4 acc[4][4];
#pragma unroll
  for (int i = 0; i < 4; ++i)
#pragma unroll
    for (int j = 0; j < 4; ++j) acc[i][j] = (f32x4){0.f, 0.f, 0.f, 0.f};

  const int arow = t >> 2;                                  // 0..63
  const int acol = ((t & 3) ^ ((t >> 3) & 3)) * 8;          // pre-swizzled src
  const char* Ag = (const char*)(A + (long)(m0 + arow) * K + acol);
  const char* Bg = (const char*)(Bt + (long)(n0 + arow) * K + acol);
  const long rowskip = (long)64 * K * 2;
  const int rdsw = (g ^ ((r16 >> 1) & 3)) * 8;              // read-side slot

  auto stage = [&](int buf, long koff) {
    char* AsW = (char*)As[buf] + w * 1024;
    char* BsW = (char*)Bs[buf] + w * 1024;
    gload_lds16(Ag + koff, AsW);
    gload_lds16(Ag + koff + rowskip, AsW + 4096);
    gload_lds16(Bg + koff, BsW);
    gload_lds16(Bg + koff + rowskip, BsW + 4096);
  };

  stage(0, 0);
  __syncthreads();

  for (int kt = 0; kt < K; kt += 32) {
    const int cur = (kt >> 5) & 1;
    if (kt + 32 < K) stage(cur ^ 1, (long)(kt + 32) * 2);
    bf16x8 af[4], bfr[4];
#pragma unroll
    for (int mi = 0; mi < 4; ++mi)
      af[mi] = *reinterpret_cast<const bf16x8*>(
          &As[cur][(wr * 64 + mi * 16 + r16) * 32 + rdsw]);
#pragma unroll
    for (int ni = 0; ni < 4; ++ni)
      bfr[ni] = *reinterpret_cast<const bf16x8*>(
          &Bs[cur][(wc * 64 + ni * 16 + r16) * 32 + rdsw]);
    __builtin_amdgcn_s_setprio(1);
#pragma unroll
    for (int mi = 0; mi < 4; ++mi)
#pragma unroll
      for (int ni = 0; ni < 4; ++ni)
        acc[mi][ni] = __builtin_amdgcn_mfma_f32_16x16x32_bf16(af[mi], bfr[ni], acc[mi][ni], 0, 0, 0);
    __builtin_amdgcn_s_setprio(0);
    __syncthreads();
  }

  if (EPI == 0) {
    const int which = n0 >> 10;
    __bf16* qkvb = (__bf16*)Cout;
#pragma unroll
    for (int mi = 0; mi < 4; ++mi) {
#pragma unroll
      for (int ni = 0; ni < 4; ++ni) {
        const int n = n0 + wc * 64 + ni * 16 + r16;
        const float bv = bias[n];
        f32x4 c = acc[mi][ni];
        const int rem = n & 1023, h = rem >> 6, hd = rem & 63;
        const int mbase = m0 + wr * 64 + mi * 16 + g * 4;
        const int b = mbase >> 11, tt0 = mbase & 2047;
        if (which < 2) {
#pragma unroll
          for (int r = 0; r < 4; ++r)
            qkvb[((long)((which * B_ + b) * H_ + h) * T_ + tt0 + r) * HD_ + hd] =
                (__bf16)(c[r] + bv);
        } else {
          bf16x4 pk = { (__bf16)(c[0] + bv), (__bf16)(c[1] + bv),
                        (__bf16)(c[2] + bv), (__bf16)(c[3] + bv) };
          *reinterpret_cast<bf16x4*>(
              &vout[(((long)b * H_ + h) * HD_ + hd) * T_ + tt0]) = pk;
        }
      }
    }
  } else {
    float* O = (float*)Cout;
#pragma unroll
    for (int mi = 0; mi < 4; ++mi) {
#pragma unroll
      for (int ni = 0; ni < 4; ++ni) {
        const int n = n0 + wc * 64 + ni * 16 + r16;
        const float bv = bias[n];
        f32x4 c = acc[mi][ni];
        const int mbase = m0 + wr * 64 + mi * 16 + g * 4;
#pragma unroll
        for (int r = 0; r < 4; ++r) O[(long)(mbase + r) * N + n] = c[r] + bv;
      }
    }
  }
}

// ---------------------------------------------------------------- attention
// Swapped-QK^T softmax, Q pre-scaled (log2-domain), no max tracking,
// raw v_exp_f32, in-register P via cvt_pk + permlane32/16 swaps.
__device__ __forceinline__ void soft_side(
    const f32x4 (&s)[4], float& lrun, bool diag, int qrel,
    int g, int r16, bf16x8& pa0, bf16x8& pa1) {
  float p[4][4];
#pragma unroll
  for (int nf = 0; nf < 4; ++nf) {
#pragma unroll
    for (int rr = 0; rr < 4; ++rr) {
      float x = s[nf][rr];
      if (diag) x = (nf * 16 + 4 * g + rr <= qrel + r16) ? x : -1e30f;
      p[nf][rr] = __builtin_amdgcn_exp2f(x);  // 2^-1e30 -> +0
    }
  }
  const float ps0 = (p[0][0] + p[0][1]) + (p[0][2] + p[0][3]);
  const float ps1 = (p[1][0] + p[1][1]) + (p[1][2] + p[1][3]);
  const float ps2 = (p[2][0] + p[2][1]) + (p[2][2] + p[2][3]);
  const float ps3 = (p[3][0] + p[3][1]) + (p[3][2] + p[3][3]);
  lrun += (ps0 + ps1) + (ps2 + ps3);

  unsigned u[4][2];
#pragma unroll
  for (int nf = 0; nf < 4; ++nf) {
    asm("v_cvt_pk_bf16_f32 %0, %1, %2"
        : "=v"(u[nf][0]) : "v"(p[nf][0]), "v"(p[nf][1]));
    asm("v_cvt_pk_bf16_f32 %0, %1, %2"
        : "=v"(u[nf][1]) : "v"(p[nf][2]), "v"(p[nf][3]));
  }
#pragma unroll
  for (int j = 0; j < 2; ++j) {
    asm("v_permlane32_swap_b32 %0, %1" : "+v"(u[0][j]), "+v"(u[1][j]));
    asm("v_permlane32_swap_b32 %0, %1" : "+v"(u[2][j]), "+v"(u[3][j]));
  }
#pragma unroll
  for (int j = 0; j < 2; ++j) {
    asm("v_permlane16_swap_b32 %0, %1" : "+v"(u[0][j]), "+v"(u[1][j]));
    asm("v_permlane16_swap_b32 %0, %1" : "+v"(u[2][j]), "+v"(u[3][j]));
  }
  union PU { unsigned w[4]; bf16x8 v; };
  PU a0, a1;
  a0.w[0] = u[0][0]; a0.w[1] = u[0][1]; a0.w[2] = u[1][0]; a0.w[3] = u[1][1];
  a1.w[0] = u[2][0]; a1.w[1] = u[2][1]; a1.w[2] = u[3][0]; a1.w[3] = u[3][1];
  pa0 = a0.v;
  pa1 = a1.v;
}

// 32 q-rows/wave: block = 4 waves x 32 rows = 128-row q-tile. Each K/V
// LDS fragment feeds 4 MFMAs (lo/hi group) instead of 2 -> per-q LDS read
// bytes HALVED (round-11 analysis: 16 ds_read_b128/wave-iter ~= 42us of
// chip LDS-pipe time was the attn floor). Staging tiles/bh: 528 -> 272.
// grid (bh=64, y=16), qt=15-y (LPT longest-first; backfill preserved:
// 1024 blocks, ~3 resident/CU). bh fast-varying -> same-bh blocks on the
// same XCD. Round-3 lesson: no min-waves bound. Round-9 lesson: keep
// 4-wave blocks + shared staging.
__global__ __launch_bounds__(256) void k_attn(
    const __bf16* __restrict__ q, const __bf16* __restrict__ k,
    const __bf16* __restrict__ vt, __bf16* __restrict__ o) {
  __shared__ alignas(16) __bf16 Ks[2][64 * 64];
  __shared__ alignas(16) __bf16 Vs[2][64 * 64];
  const int t = threadIdx.x, w = t >> 6, l = t & 63;
  const int g = l >> 4, r16 = l & 15;
  const int bh = blockIdx.x;
  const int qt = 15 - blockIdx.y;
  const int qbaseW = qt * 128 + w * 32;       // wave's 32-row base
  const int gbaseLo = qbaseW, gbaseHi = qbaseW + 16;
  const float sc = 0.125f * 1.44269504088896341f;  // 1/sqrt(64) * log2(e)

  auto scale8 = [&](bf16x8 v) {
    bf16x8 r;
#pragma unroll
    for (int j = 0; j < 8; ++j) r[j] = (__bf16)((float)v[j] * sc);
    return r;
  };
  const __bf16* qpLo = q + ((long)bh * T_ + gbaseLo + r16) * HD_ + g * 8;
  const bf16x8 aqLo0 = scale8(*reinterpret_cast<const bf16x8*>(qpLo));
  const bf16x8 aqLo1 = scale8(*reinterpret_cast<const bf16x8*>(qpLo + 32));
  const __bf16* qpHi = q + ((long)bh * T_ + gbaseHi + r16) * HD_ + g * 8;
  const bf16x8 aqHi0 = scale8(*reinterpret_cast<const bf16x8*>(qpHi));
  const bf16x8 aqHi1 = scale8(*reinterpret_cast<const bf16x8*>(qpHi + 32));

  f32x4 oLo[4], oHi[4];
  float lLo = 0.f, lHi = 0.f;
#pragma unroll
  for (int i = 0; i < 4; ++i) {
    oLo[i] = (f32x4){0.f, 0.f, 0.f, 0.f};
    oHi[i] = (f32x4){0.f, 0.f, 0.f, 0.f};
  }

  const int srow = t >> 3, sslot = t & 7;
  const int sswz = sslot ^ (srow & 7);
  const char* kg = (const char*)(k + ((long)bh * T_ + srow) * HD_) + sswz * 16;
  const char* vg = (const char*)(vt + ((long)bh * HD_ + srow) * T_) + sswz * 16;

  auto stage = [&](int buf, int kv0) {
    char* Kd = (char*)Ks[buf] + w * 1024;
    char* Vd = (char*)Vs[buf] + w * 1024;
    gload_lds16(kg + (long)kv0 * 128, Kd);
    gload_lds16(kg + (long)kv0 * 128 + 32 * 128, Kd + 4096);
    gload_lds16(vg + (long)kv0 * 2, Vd);
    gload_lds16(vg + (long)kv0 * 2 + 32 * (long)T_ * 2, Vd + 4096);
  };

  stage(0, 0);
  __syncthreads();

  const int ntile = qt * 2 + 2;               // covers kv rows 0..qt*128+127
  for (int it = 0; it < ntile; ++it) {
    const int cur = it & 1;
    if (it + 1 < ntile) stage(cur ^ 1, (it + 1) * 64);
    const char* Kc = (const char*)Ks[cur];
    const char* Vc = (const char*)Vs[cur];
    const int kv0 = it * 64;
    const bool live = kv0 <= qbaseW + 31;     // wave-uniform: any unmasked?

    if (live) {
      const bool diagLo = (kv0 + 63) > gbaseLo;
      const bool diagHi = (kv0 + 63) > gbaseHi;

      f32x4 sLo[4], sHi[4];
      __builtin_amdgcn_s_setprio(1);
#pragma unroll
      for (int nf = 0; nf < 4; ++nf) {
        const char* kb = Kc + (nf * 16 + r16) * 128;
        const bf16x8 b0 = *reinterpret_cast<const bf16x8*>(kb + ((g ^ (r16 & 7)) << 4));
        const bf16x8 b1 = *reinterpret_cast<const bf16x8*>(kb + (((4 + g) ^ (r16 & 7)) << 4));
        f32x4 z = (f32x4){0.f, 0.f, 0.f, 0.f};
        z = __builtin_amdgcn_mfma_f32_16x16x32_bf16(b0, aqLo0, z, 0, 0, 0);
        z = __builtin_amdgcn_mfma_f32_16x16x32_bf16(b1, aqLo1, z, 0, 0, 0);
        sLo[nf] = z;
        f32x4 zh = (f32x4){0.f, 0.f, 0.f, 0.f};
        zh = __builtin_amdgcn_mfma_f32_16x16x32_bf16(b0, aqHi0, zh, 0, 0, 0);
        zh = __builtin_amdgcn_mfma_f32_16x16x32_bf16(b1, aqHi1, zh, 0, 0, 0);
        sHi[nf] = zh;
      }
      __builtin_amdgcn_s_setprio(0);

      bf16x8 paLo0, paLo1, paHi0, paHi1;
      soft_side(sLo, lLo, diagLo, gbaseLo - kv0, g, r16, paLo0, paLo1);
      soft_side(sHi, lHi, diagHi, gbaseHi - kv0, g, r16, paHi0, paHi1);

      __builtin_amdgcn_s_setprio(1);
#pragma unroll
      for (int nf = 0; nf < 4; ++nf) {
        const char* vb = Vc + (nf * 16 + r16) * 128;
        const bf16x8 v0 = *reinterpret_cast<const bf16x8*>(vb + ((g ^ (r16 & 7)) << 4));
        const bf16x8 v1 = *reinterpret_cast<const bf16x8*>(vb + (((4 + g) ^ (r16 & 7)) << 4));
        oLo[nf] = __builtin_amdgcn_mfma_f32_16x16x32_bf16(paLo0, v0, oLo[nf], 0, 0, 0);
        oLo[nf] = __builtin_amdgcn_mfma_f32_16x16x32_bf16(paLo1, v1, oLo[nf], 0, 0, 0);
        oHi[nf] = __builtin_amdgcn_mfma_f32_16x16x32_bf16(paHi0, v0, oHi[nf], 0, 0, 0);
        oHi[nf] = __builtin_amdgcn_mfma_f32_16x16x32_bf16(paHi1, v1, oHi[nf], 0, 0, 0);
      }
      __builtin_amdgcn_s_setprio(0);
    }
    __syncthreads();
  }

  lLo += __shfl_xor(lLo, 16, 64);
  lLo += __shfl_xor(lLo, 32, 64);
  lHi += __shfl_xor(lHi, 16, 64);
  lHi += __shfl_xor(lHi, 32, 64);
  const float invLo = 1.f / lLo, invHi = 1.f / lHi;
  float invLoQ[4], invHiQ[4];
#pragma unroll
  for (int rr = 0; rr < 4; ++rr) {
    invLoQ[rr] = __shfl(invLo, 4 * g + rr, 64);
    invHiQ[rr] = __shfl(invHi, 4 * g + rr, 64);
  }
  const int b = bh >> 4, h = bh & 15;
#pragma unroll
  for (int nf = 0; nf < 4; ++nf) {
    const int hd = nf * 16 + r16;
#pragma unroll
    for (int rr = 0; rr < 4; ++rr) {
      const int ttLo = gbaseLo + g * 4 + rr;
      o[((long)b * T_ + ttLo) * D_ + h * HD_ + hd] = (__bf16)(oLo[nf][rr] * invLoQ[rr]);
      const int ttHi = gbaseHi + g * 4 + rr;
      o[((long)b * T_ + ttHi) * D_ + h * HD_ + hd] = (__bf16)(oHi[nf][rr] * invHiQ[rr]);
    }
  }
}

// ---------------------------------------------------------------- launcher
extern "C" void kernel_launch(void* const* d_in, const int* in_sizes, int n_in,
                              void* d_out, int out_size, void* d_ws, size_t ws_size,
                              hipStream_t stream) {
  (void)in_sizes; (void)n_in; (void)out_size; (void)ws_size;
  const float* x     = (const float*)d_in[0];
  const float* Wqkv  = (const float*)d_in[1];
  const float* bqkv  = (const float*)d_in[2];
  const float* Wproj = (const float*)d_in[3];
  const float* bproj = (const float*)d_in[4];
  float* out = (float*)d_out;

  const long MT = (long)B_ * T_;          // 8192
  __bf16* xb     = (__bf16*)d_ws;                    // [8192][1024]
  __bf16* wqkvt  = xb + MT * D_;                     // [3072][1024]
  __bf16* wprojt = wqkvt + (long)3 * D_ * D_;        // [1024][1024]
  __bf16* qkvb   = wprojt + (long)D_ * D_;           // q,k: [2][B][H][T][64]
  __bf16* vtb    = qkvb + (long)2 * B_ * H_ * T_ * HD_;  // [B][H][64][T]
  __bf16* attno  = vtb + (long)B_ * H_ * HD_ * T_;   // [8192][1024]

  k_cvt_f32_bf16<<<2048, 256, 0, stream>>>(x, xb, (int)(MT * D_ / 4));
  k_transpose_bf16<float><<<dim3(48, 16, 1), 256, 0, stream>>>(Wqkv, wqkvt, D_, 3 * D_, 0, 0);
  k_transpose_bf16<float><<<dim3(16, 16, 1), 256, 0, stream>>>(Wproj, wprojt, D_, D_, 0, 0);
  k_gemm_bt<0><<<dim3(24, 64), 256, 0, stream>>>(xb, wqkvt, bqkv, qkvb, vtb, 8192, 3072, 1024);
  k_attn<<<dim3(64, 16), 256, 0, stream>>>(
      qkvb, qkvb + (long)B_ * H_ * T_ * HD_, vtb, attno);
  k_gemm_bt<1><<<dim3(8, 64), 256, 0, stream>>>(attno, wprojt, bproj, out, nullptr, 8192, 1024, 1024);
}

// Round 13
// 161.424 us; speedup vs baseline: 1.0784x; 1.0784x over previous
//
#include <hip/hip_runtime.h>

typedef float f32x4 __attribute__((ext_vector_type(4)));
typedef __bf16 bf16x8 __attribute__((ext_vector_type(8)));
typedef __bf16 bf16x4 __attribute__((ext_vector_type(4)));

#define B_ 4
#define T_ 2048
#define D_ 1024
#define H_ 16
#define HD_ 64

__device__ __forceinline__ void gload_lds16(const void* g, void* l) {
  __builtin_amdgcn_global_load_lds(
      (const __attribute__((address_space(1))) void*)g,
      (__attribute__((address_space(3))) void*)l, 16, 0, 0);
}

// ---------------------------------------------------------------- convert x
__global__ __launch_bounds__(256) void k_cvt_f32_bf16(
    const float* __restrict__ in, __bf16* __restrict__ out, int n4) {
  int i = blockIdx.x * blockDim.x + threadIdx.x;
  int stride = gridDim.x * blockDim.x;
  for (; i < n4; i += stride) {
    float4 v = reinterpret_cast<const float4*>(in)[i];
    bf16x4 o = { (__bf16)v.x, (__bf16)v.y, (__bf16)v.z, (__bf16)v.w };
    reinterpret_cast<bf16x4*>(out)[i] = o;
  }
}

// ------------------------------------------- transpose (+convert) to bf16
template <typename Tin>
__global__ __launch_bounds__(256) void k_transpose_bf16(
    const Tin* __restrict__ in, __bf16* __restrict__ out,
    int R, int C, long inb, long outb) {
  __shared__ alignas(16) __bf16 lds[64 * 68];
  const int t = threadIdx.x;
  in  += (long)blockIdx.z * inb;
  out += (long)blockIdx.z * outb;
  const int r0 = blockIdx.y * 64, c0 = blockIdx.x * 64;
#pragma unroll
  for (int i = 0; i < 16; ++i) {
    int e = i * 256 + t, row = e >> 6, col = e & 63;
    lds[row * 68 + col] = (__bf16)(float)in[(long)(r0 + row) * C + c0 + col];
  }
  __syncthreads();
#pragma unroll
  for (int i = 0; i < 16; ++i) {
    int e = i * 256 + t, orow = e >> 6, ocol = e & 63;
    out[(long)(c0 + orow) * R + r0 + ocol] = lds[ocol * 68 + orow];
  }
}

// -------------------------------------------------------- QKV GEMM (256^2)
// BM=BN=256, BK=64, 512 thr (8 waves 2Mx4N, 128x64 per wave), 128KB dbuf
// LDS, counted-vmcnt schedule: per K-tile {barrier; issue A(kt+1) 4 loads;
// vmcnt(4) [drains tile-kt's 8 older loads, keeps 4 in flight]; barrier;
// phase0 (ds_read 12 + 32 MFMA); issue B(kt+1) 4 loads; phase1}. Loads
// are never drained to 0 in the loop (T3+T4). 8-slot XOR swizzle via
// pre-swizzled global source (gload_lds dest linear), read-side XOR.
__global__ __launch_bounds__(512) void k_gemm256_qkv(
    const __bf16* __restrict__ A, const __bf16* __restrict__ Bt,
    const float* __restrict__ bias, __bf16* __restrict__ qkvb,
    __bf16* __restrict__ vout) {
  __shared__ alignas(16) __bf16 lds[2][2][256 * 64];  // [buf][A/B][row*64+col]
  const int t = threadIdx.x;                 // 0..511
  const int w = t >> 6, l = t & 63;
  const int g = l >> 4, r16 = l & 15;
  const int wm = w >> 2, wn = w & 3;         // 2 x 4 wave grid
  const int m0 = blockIdx.y * 256, n0 = blockIdx.x * 256;
  const int K = 1024, NT = 16;

  f32x4 acc[8][4];
#pragma unroll
  for (int i = 0; i < 8; ++i)
#pragma unroll
    for (int j = 0; j < 4; ++j) acc[i][j] = (f32x4){0.f, 0.f, 0.f, 0.f};

  // staging: e = c*512 + t ; row = e>>3 ; phys slot = e&7 ;
  // global col = (phys ^ (row&7))*8 ; lds dest linear = e*16 bytes.
  auto stageA = [&](int buf, int kt) {
#pragma unroll
    for (int c = 0; c < 4; ++c) {
      const int e = c * 512 + t;
      const int row = e >> 3, p = e & 7;
      gload_lds16(A + (long)(m0 + row) * K + kt * 64 + ((p ^ (row & 7)) << 3),
                  (char*)&lds[buf][0][0] + (c * 512 + w * 64) * 16);
    }
  };
  auto stageB = [&](int buf, int kt) {
#pragma unroll
    for (int c = 0; c < 4; ++c) {
      const int e = c * 512 + t;
      const int row = e >> 3, p = e & 7;
      gload_lds16(Bt + (long)(n0 + row) * K + kt * 64 + ((p ^ (row & 7)) << 3),
                  (char*)&lds[buf][1][0] + (c * 512 + w * 64) * 16);
    }
  };

  stageA(0, 0);
  stageB(0, 0);

  for (int kt = 0; kt < NT; ++kt) {
    const int cur = kt & 1;
    const int kn = (kt + 1 < NT) ? kt + 1 : kt;  // last tile: dummy re-stage
    __builtin_amdgcn_s_barrier();        // all reads of buf cur^1 finished
    stageA(cur ^ 1, kn);                 // 4 loads (tile kt+1 A)
    asm volatile("s_waitcnt vmcnt(4)" ::: "memory");  // tile kt (8) landed
    __builtin_amdgcn_sched_barrier(0);
    __builtin_amdgcn_s_barrier();        // publish tile kt to all waves
    const __bf16* Ab = &lds[cur][0][0];
    const __bf16* Bb = &lds[cur][1][0];

#pragma unroll
    for (int ks = 0; ks < 2; ++ks) {
      bf16x8 afr[8], bfr[4];
      const int slot = ((ks * 4 + g) ^ (r16 & 7)) << 3;
#pragma unroll
      for (int mi = 0; mi < 8; ++mi)
        afr[mi] = *reinterpret_cast<const bf16x8*>(
            &Ab[(wm * 128 + mi * 16 + r16) * 64 + slot]);
#pragma unroll
      for (int ni = 0; ni < 4; ++ni)
        bfr[ni] = *reinterpret_cast<const bf16x8*>(
            &Bb[(wn * 64 + ni * 16 + r16) * 64 + slot]);
      __builtin_amdgcn_s_setprio(1);
#pragma unroll
      for (int mi = 0; mi < 8; ++mi)
#pragma unroll
        for (int ni = 0; ni < 4; ++ni)
          acc[mi][ni] = __builtin_amdgcn_mfma_f32_16x16x32_bf16(
              afr[mi], bfr[ni], acc[mi][ni], 0, 0, 0);
      __builtin_amdgcn_s_setprio(0);
      if (ks == 0) stageB(cur ^ 1, kn);  // 4 loads (tile kt+1 B)
    }
  }
  asm volatile("s_waitcnt vmcnt(0)" ::: "memory");  // drain before epilogue

  // epilogue: q,k scattered bf16; v packed bf16x4 to [B][H][64][T].
  const int which = n0 >> 10;            // block-uniform (256 | 1024)
#pragma unroll
  for (int mi = 0; mi < 8; ++mi) {
#pragma unroll
    for (int ni = 0; ni < 4; ++ni) {
      const int n = n0 + wn * 64 + ni * 16 + r16;
      const float bv = bias[n];
      f32x4 c = acc[mi][ni];
      const int rem = n & 1023, h = rem >> 6, hd = rem & 63;
      const int mbase = m0 + wm * 128 + mi * 16 + g * 4;
      const int b = mbase >> 11, tt0 = mbase & 2047;
      if (which < 2) {
#pragma unroll
        for (int r = 0; r < 4; ++r)
          qkvb[((long)((which * B_ + b) * H_ + h) * T_ + tt0 + r) * HD_ + hd] =
              (__bf16)(c[r] + bv);
      } else {
        bf16x4 pk = { (__bf16)(c[0] + bv), (__bf16)(c[1] + bv),
                      (__bf16)(c[2] + bv), (__bf16)(c[3] + bv) };
        *reinterpret_cast<bf16x4*>(
            &vout[(((long)b * H_ + h) * HD_ + hd) * T_ + tt0]) = pk;
      }
    }
  }
}

// ---------------------------------------------------------------- GEMM (bt)
// 128x128 tile, BK=32, 2-phase dbuf, XOR-swizzled LDS (proj output only).
template <int EPI>
__global__ __launch_bounds__(256) void k_gemm_bt(
    const __bf16* __restrict__ A, const __bf16* __restrict__ Bt,
    const float* __restrict__ bias, void* __restrict__ Cout,
    __bf16* __restrict__ vout, int M, int N, int K) {
  __shared__ alignas(16) __bf16 As[2][128 * 32];
  __shared__ alignas(16) __bf16 Bs[2][128 * 32];
  const int t = threadIdx.x;
  const int w = t >> 6, l = t & 63;
  const int g = l >> 4, r16 = l & 15;
  const int wr = w >> 1, wc = w & 1;
  const int m0 = blockIdx.y * 128, n0 = blockIdx.x * 128;

  f32x4 acc[4][4];
#pragma unroll
  for (int i = 0; i < 4; ++i)
#pragma unroll
    for (int j = 0; j < 4; ++j) acc[i][j] = (f32x4){0.f, 0.f, 0.f, 0.f};

  const int arow = t >> 2;
  const int acol = ((t & 3) ^ ((t >> 3) & 3)) * 8;
  const char* Ag = (const char*)(A + (long)(m0 + arow) * K + acol);
  const char* Bg = (const char*)(Bt + (long)(n0 + arow) * K + acol);
  const long rowskip = (long)64 * K * 2;
  const int rdsw = (g ^ ((r16 >> 1) & 3)) * 8;

  auto stage = [&](int buf, long koff) {
    char* AsW = (char*)As[buf] + w * 1024;
    char* BsW = (char*)Bs[buf] + w * 1024;
    gload_lds16(Ag + koff, AsW);
    gload_lds16(Ag + koff + rowskip, AsW + 4096);
    gload_lds16(Bg + koff, BsW);
    gload_lds16(Bg + koff + rowskip, BsW + 4096);
  };

  stage(0, 0);
  __syncthreads();

  for (int kt = 0; kt < K; kt += 32) {
    const int cur = (kt >> 5) & 1;
    if (kt + 32 < K) stage(cur ^ 1, (long)(kt + 32) * 2);
    bf16x8 af[4], bfr[4];
#pragma unroll
    for (int mi = 0; mi < 4; ++mi)
      af[mi] = *reinterpret_cast<const bf16x8*>(
          &As[cur][(wr * 64 + mi * 16 + r16) * 32 + rdsw]);
#pragma unroll
    for (int ni = 0; ni < 4; ++ni)
      bfr[ni] = *reinterpret_cast<const bf16x8*>(
          &Bs[cur][(wc * 64 + ni * 16 + r16) * 32 + rdsw]);
    __builtin_amdgcn_s_setprio(1);
#pragma unroll
    for (int mi = 0; mi < 4; ++mi)
#pragma unroll
      for (int ni = 0; ni < 4; ++ni)
        acc[mi][ni] = __builtin_amdgcn_mfma_f32_16x16x32_bf16(af[mi], bfr[ni], acc[mi][ni], 0, 0, 0);
    __builtin_amdgcn_s_setprio(0);
    __syncthreads();
  }

  if (EPI == 0) {
    const int which = n0 >> 10;
    __bf16* qkvb = (__bf16*)Cout;
#pragma unroll
    for (int mi = 0; mi < 4; ++mi) {
#pragma unroll
      for (int ni = 0; ni < 4; ++ni) {
        const int n = n0 + wc * 64 + ni * 16 + r16;
        const float bv = bias[n];
        f32x4 c = acc[mi][ni];
        const int rem = n & 1023, h = rem >> 6, hd = rem & 63;
        const int mbase = m0 + wr * 64 + mi * 16 + g * 4;
        const int b = mbase >> 11, tt0 = mbase & 2047;
        if (which < 2) {
#pragma unroll
          for (int r = 0; r < 4; ++r)
            qkvb[((long)((which * B_ + b) * H_ + h) * T_ + tt0 + r) * HD_ + hd] =
                (__bf16)(c[r] + bv);
        } else {
          bf16x4 pk = { (__bf16)(c[0] + bv), (__bf16)(c[1] + bv),
                        (__bf16)(c[2] + bv), (__bf16)(c[3] + bv) };
          *reinterpret_cast<bf16x4*>(
              &vout[(((long)b * H_ + h) * HD_ + hd) * T_ + tt0]) = pk;
        }
      }
    }
  } else {
    float* O = (float*)Cout;
#pragma unroll
    for (int mi = 0; mi < 4; ++mi) {
#pragma unroll
      for (int ni = 0; ni < 4; ++ni) {
        const int n = n0 + wc * 64 + ni * 16 + r16;
        const float bv = bias[n];
        f32x4 c = acc[mi][ni];
        const int mbase = m0 + wr * 64 + mi * 16 + g * 4;
#pragma unroll
        for (int r = 0; r < 4; ++r) O[(long)(mbase + r) * N + n] = c[r] + bv;
      }
    }
  }
}

// ---------------------------------------------------------------- attention
// (round-11 version, the measured optimum of this family)
__device__ __forceinline__ void soft_side(
    const f32x4 (&s)[4], float& lrun, bool diag, int qrel,
    int g, int r16, bf16x8& pa0, bf16x8& pa1) {
  float p[4][4];
#pragma unroll
  for (int nf = 0; nf < 4; ++nf) {
#pragma unroll
    for (int rr = 0; rr < 4; ++rr) {
      float x = s[nf][rr];
      if (diag) x = (nf * 16 + 4 * g + rr <= qrel + r16) ? x : -1e30f;
      p[nf][rr] = __builtin_amdgcn_exp2f(x);  // 2^-1e30 -> +0
    }
  }
  const float ps0 = (p[0][0] + p[0][1]) + (p[0][2] + p[0][3]);
  const float ps1 = (p[1][0] + p[1][1]) + (p[1][2] + p[1][3]);
  const float ps2 = (p[2][0] + p[2][1]) + (p[2][2] + p[2][3]);
  const float ps3 = (p[3][0] + p[3][1]) + (p[3][2] + p[3][3]);
  lrun += (ps0 + ps1) + (ps2 + ps3);

  unsigned u[4][2];
#pragma unroll
  for (int nf = 0; nf < 4; ++nf) {
    asm("v_cvt_pk_bf16_f32 %0, %1, %2"
        : "=v"(u[nf][0]) : "v"(p[nf][0]), "v"(p[nf][1]));
    asm("v_cvt_pk_bf16_f32 %0, %1, %2"
        : "=v"(u[nf][1]) : "v"(p[nf][2]), "v"(p[nf][3]));
  }
#pragma unroll
  for (int j = 0; j < 2; ++j) {
    asm("v_permlane32_swap_b32 %0, %1" : "+v"(u[0][j]), "+v"(u[1][j]));
    asm("v_permlane32_swap_b32 %0, %1" : "+v"(u[2][j]), "+v"(u[3][j]));
  }
#pragma unroll
  for (int j = 0; j < 2; ++j) {
    asm("v_permlane16_swap_b32 %0, %1" : "+v"(u[0][j]), "+v"(u[1][j]));
    asm("v_permlane16_swap_b32 %0, %1" : "+v"(u[2][j]), "+v"(u[3][j]));
  }
  union PU { unsigned w[4]; bf16x8 v; };
  PU a0, a1;
  a0.w[0] = u[0][0]; a0.w[1] = u[0][1]; a0.w[2] = u[1][0]; a0.w[3] = u[1][1];
  a1.w[0] = u[2][0]; a1.w[1] = u[2][1]; a1.w[2] = u[3][0]; a1.w[3] = u[3][1];
  pa0 = a0.v;
  pa1 = a1.v;
}

__global__ __launch_bounds__(256) void k_attn(
    const __bf16* __restrict__ q, const __bf16* __restrict__ k,
    const __bf16* __restrict__ vt, __bf16* __restrict__ o) {
  __shared__ alignas(16) __bf16 Ks[2][64 * 64];
  __shared__ alignas(16) __bf16 Vs[2][64 * 64];
  const int t = threadIdx.x, w = t >> 6, l = t & 63;
  const int g = l >> 4, r16 = l & 15;
  const int bh = blockIdx.x;
  const int qt = 31 - blockIdx.y;
  const int qbase = qt * 64 + w * 16;
  const float sc = 0.125f * 1.44269504088896341f;  // 1/sqrt(64) * log2(e)

  auto scale8 = [&](bf16x8 v) {
    bf16x8 r;
#pragma unroll
    for (int j = 0; j < 8; ++j) r[j] = (__bf16)((float)v[j] * sc);
    return r;
  };
  const __bf16* qp = q + ((long)bh * T_ + qbase + r16) * HD_ + g * 8;
  const bf16x8 aq0 = scale8(*reinterpret_cast<const bf16x8*>(qp));
  const bf16x8 aq1 = scale8(*reinterpret_cast<const bf16x8*>(qp + 32));

  f32x4 oacc[4];
  float lrun = 0.f;
#pragma unroll
  for (int i = 0; i < 4; ++i) oacc[i] = (f32x4){0.f, 0.f, 0.f, 0.f};

  const int srow = t >> 3, sslot = t & 7;
  const int sswz = sslot ^ (srow & 7);
  const char* kg = (const char*)(k + ((long)bh * T_ + srow) * HD_) + sswz * 16;
  const char* vg = (const char*)(vt + ((long)bh * HD_ + srow) * T_) + sswz * 16;

  auto stage = [&](int buf, int kv0) {
    char* Kd = (char*)Ks[buf] + w * 1024;
    char* Vd = (char*)Vs[buf] + w * 1024;
    gload_lds16(kg + (long)kv0 * 128, Kd);
    gload_lds16(kg + (long)kv0 * 128 + 32 * 128, Kd + 4096);
    gload_lds16(vg + (long)kv0 * 2, Vd);
    gload_lds16(vg + (long)kv0 * 2 + 32 * (long)T_ * 2, Vd + 4096);
  };

  stage(0, 0);
  __syncthreads();

  const int ntile = qt + 1;
  for (int it = 0; it < ntile; ++it) {
    const int cur = it & 1;
    if (it + 1 < ntile) stage(cur ^ 1, (it + 1) * 64);
    const char* Kc = (const char*)Ks[cur];
    const char* Vc = (const char*)Vs[cur];

    f32x4 s[4];
    __builtin_amdgcn_s_setprio(1);
#pragma unroll
    for (int nf = 0; nf < 4; ++nf) {
      const char* kb = Kc + (nf * 16 + r16) * 128;
      const bf16x8 b0 = *reinterpret_cast<const bf16x8*>(kb + ((g ^ (r16 & 7)) << 4));
      const bf16x8 b1 = *reinterpret_cast<const bf16x8*>(kb + (((4 + g) ^ (r16 & 7)) << 4));
      f32x4 z = (f32x4){0.f, 0.f, 0.f, 0.f};
      z = __builtin_amdgcn_mfma_f32_16x16x32_bf16(b0, aq0, z, 0, 0, 0);
      z = __builtin_amdgcn_mfma_f32_16x16x32_bf16(b1, aq1, z, 0, 0, 0);
      s[nf] = z;
    }
    __builtin_amdgcn_s_setprio(0);

    bf16x8 pa0, pa1;
    soft_side(s, lrun, it == qt, qbase - it * 64, g, r16, pa0, pa1);

    __builtin_amdgcn_s_setprio(1);
#pragma unroll
    for (int nf = 0; nf < 4; ++nf) {
      const char* vb = Vc + (nf * 16 + r16) * 128;
      const bf16x8 v0 = *reinterpret_cast<const bf16x8*>(vb + ((g ^ (r16 & 7)) << 4));
      const bf16x8 v1 = *reinterpret_cast<const bf16x8*>(vb + (((4 + g) ^ (r16 & 7)) << 4));
      oacc[nf] = __builtin_amdgcn_mfma_f32_16x16x32_bf16(pa0, v0, oacc[nf], 0, 0, 0);
      oacc[nf] = __builtin_amdgcn_mfma_f32_16x16x32_bf16(pa1, v1, oacc[nf], 0, 0, 0);
    }
    __builtin_amdgcn_s_setprio(0);
    __syncthreads();
  }

  lrun += __shfl_xor(lrun, 16, 64);
  lrun += __shfl_xor(lrun, 32, 64);
  const float inv = 1.f / lrun;
  float invq[4];
#pragma unroll
  for (int rr = 0; rr < 4; ++rr) invq[rr] = __shfl(inv, 4 * g + rr, 64);
  const int b = bh >> 4, h = bh & 15;
#pragma unroll
  for (int nf = 0; nf < 4; ++nf) {
    const int hd = nf * 16 + r16;
#pragma unroll
    for (int rr = 0; rr < 4; ++rr) {
      const int tt = qbase + g * 4 + rr;
      o[((long)b * T_ + tt) * D_ + h * HD_ + hd] = (__bf16)(oacc[nf][rr] * invq[rr]);
    }
  }
}

// ---------------------------------------------------------------- launcher
extern "C" void kernel_launch(void* const* d_in, const int* in_sizes, int n_in,
                              void* d_out, int out_size, void* d_ws, size_t ws_size,
                              hipStream_t stream) {
  (void)in_sizes; (void)n_in; (void)out_size; (void)ws_size;
  const float* x     = (const float*)d_in[0];
  const float* Wqkv  = (const float*)d_in[1];
  const float* bqkv  = (const float*)d_in[2];
  const float* Wproj = (const float*)d_in[3];
  const float* bproj = (const float*)d_in[4];
  float* out = (float*)d_out;

  const long MT = (long)B_ * T_;          // 8192
  __bf16* xb     = (__bf16*)d_ws;                    // [8192][1024]
  __bf16* wqkvt  = xb + MT * D_;                     // [3072][1024]
  __bf16* wprojt = wqkvt + (long)3 * D_ * D_;        // [1024][1024]
  __bf16* qkvb   = wprojt + (long)D_ * D_;           // q,k: [2][B][H][T][64]
  __bf16* vtb    = qkvb + (long)2 * B_ * H_ * T_ * HD_;  // [B][H][64][T]
  __bf16* attno  = vtb + (long)B_ * H_ * HD_ * T_;   // [8192][1024]

  k_cvt_f32_bf16<<<2048, 256, 0, stream>>>(x, xb, (int)(MT * D_ / 4));
  k_transpose_bf16<float><<<dim3(48, 16, 1), 256, 0, stream>>>(Wqkv, wqkvt, D_, 3 * D_, 0, 0);
  k_transpose_bf16<float><<<dim3(16, 16, 1), 256, 0, stream>>>(Wproj, wprojt, D_, D_, 0, 0);
  k_gemm256_qkv<<<dim3(12, 32), 512, 0, stream>>>(xb, wqkvt, bqkv, qkvb, vtb);
  k_attn<<<dim3(64, 32), 256, 0, stream>>>(
      qkvb, qkvb + (long)B_ * H_ * T_ * HD_, vtb, attno);
  k_gemm_bt<1><<<dim3(8, 64), 256, 0, stream>>>(attno, wprojt, bproj, out, nullptr, 8192, 1024, 1024);
}